// Round 1
// baseline (335.609 us; speedup 1.0000x reference)
//
#include <hip/hip_runtime.h>
#include <math.h>

// ---------------------------------------------------------------------------
// CAM module:  q = conv2x2s2(x,Wq)+bq ; k = conv2x2s2(x,Wk)+bk
//              energy = q @ k^T ; A = softmax(rowmax - energy)
//              out = A @ (Wv@x + bv)  ==  (A@Wv) @ x  +  (A@bv)
// All fp32 (softmax is tie-sensitive; bf16 logits would flip argmins).
// ---------------------------------------------------------------------------

// ---------------- Kernel 1: stacked q/k conv as GEMM -----------------------
// A = W (128x512 row-major, p = i*4+kh*2+kw), B = patches P[512][4096]
// BM=128 BN=64 BK=16, 256 threads, TM=8 TN=4
__global__ __launch_bounds__(256) void k_qkconv(
    const float* __restrict__ x, const float* __restrict__ Wq,
    const float* __restrict__ Wk, const float* __restrict__ bq,
    const float* __restrict__ bk, float* __restrict__ qbuf,
    float* __restrict__ kbuf) {
  __shared__ float As[16][128];  // [k][m] transposed
  __shared__ float Bs[16][64];
  const int t  = threadIdx.x;
  const int nt = blockIdx.x;   // 0..63  (64 cols each)
  const int ct = blockIdx.y;   // 0: q, 1: k
  const int b  = blockIdx.z;   // 0..7
  const float* W    = ct ? Wk : Wq;
  const float* bias = ct ? bk : bq;
  float* outbuf = (ct ? kbuf : qbuf) + (size_t)b * 128 * 4096;
  const float* xb = x + (size_t)b * 128 * 128 * 128;

  const int tm = (t >> 4) * 8;
  const int tn = (t & 15) * 4;
  const int am = t >> 1;          // A-load row (0..127)
  const int ak = (t & 1) * 8;     // A-load k offset
  const int bkk = t >> 4;         // B-load k row (0..15)
  const int bn  = (t & 15) * 4;   // B-load col
  const int n_base = nt * 64;

  float acc[8][4];
#pragma unroll
  for (int r = 0; r < 8; ++r)
#pragma unroll
    for (int j = 0; j < 4; ++j) acc[r][j] = 0.f;

  for (int kk = 0; kk < 512; kk += 16) {
    const float4 a0 = *(const float4*)&W[am * 512 + kk + ak];
    const float4 a1 = *(const float4*)&W[am * 512 + kk + ak + 4];
    As[ak + 0][am] = a0.x; As[ak + 1][am] = a0.y;
    As[ak + 2][am] = a0.z; As[ak + 3][am] = a0.w;
    As[ak + 4][am] = a1.x; As[ak + 5][am] = a1.y;
    As[ak + 6][am] = a1.z; As[ak + 7][am] = a1.w;
    {
      const int p  = kk + bkk;        // patch row
      const int ci = p >> 2;
      const int kh = (p >> 1) & 1;
      const int kw = p & 1;
      const float* xr = xb + ci * 16384 + kh * 128 + kw;
#pragma unroll
      for (int j = 0; j < 4; ++j) {
        const int n  = n_base + bn + j;
        const int oh = n >> 6;
        const int ow = n & 63;
        Bs[bkk][bn + j] = xr[oh * 256 + ow * 2];
      }
    }
    __syncthreads();
#pragma unroll
    for (int k = 0; k < 16; ++k) {
      const float4 av0 = *(const float4*)&As[k][tm];
      const float4 av1 = *(const float4*)&As[k][tm + 4];
      const float4 bv4 = *(const float4*)&Bs[k][tn];
      const float aa[8] = {av0.x, av0.y, av0.z, av0.w,
                           av1.x, av1.y, av1.z, av1.w};
      const float bb[4] = {bv4.x, bv4.y, bv4.z, bv4.w};
#pragma unroll
      for (int r = 0; r < 8; ++r)
#pragma unroll
        for (int j = 0; j < 4; ++j)
          acc[r][j] = fmaf(aa[r], bb[j], acc[r][j]);
    }
    __syncthreads();
  }
#pragma unroll
  for (int r = 0; r < 8; ++r) {
    const int row = tm + r;
    const float bb = bias[row];
    float4 o;
    o.x = acc[r][0] + bb; o.y = acc[r][1] + bb;
    o.z = acc[r][2] + bb; o.w = acc[r][3] + bb;
    *(float4*)&outbuf[row * 4096 + n_base + tn] = o;
  }
}

// ---------------- Kernel 2: energy partials (q @ k^T) ----------------------
// 64x64 tile, K-split into 8 chunks of 512. grid (4, 8, 8)
__global__ __launch_bounds__(256) void k_energy(
    const float* __restrict__ qbuf, const float* __restrict__ kbuf,
    float* __restrict__ epart) {
  __shared__ float Qs[16][64];
  __shared__ float Ks[16][64];
  const int t    = threadIdx.x;
  const int tile = blockIdx.x;  // c0=(tile>>1)*64, d0=(tile&1)*64
  const int ks   = blockIdx.y;  // 0..7
  const int b    = blockIdx.z;
  const int c0 = (tile >> 1) * 64;
  const int d0 = (tile & 1) * 64;
  const float* qb = qbuf + (size_t)b * 128 * 4096;
  const float* kb = kbuf + (size_t)b * 128 * 4096;

  const int tm = (t >> 4) * 4;
  const int tn = (t & 15) * 4;
  const int lr = t >> 2;         // 0..63
  const int lk = (t & 3) * 4;

  float acc[4][4];
#pragma unroll
  for (int r = 0; r < 4; ++r)
#pragma unroll
    for (int j = 0; j < 4; ++j) acc[r][j] = 0.f;

  const int k_begin = ks * 512;
  for (int kk = k_begin; kk < k_begin + 512; kk += 16) {
    const float4 qv = *(const float4*)&qb[(c0 + lr) * 4096 + kk + lk];
    const float4 kv = *(const float4*)&kb[(d0 + lr) * 4096 + kk + lk];
    Qs[lk + 0][lr] = qv.x; Qs[lk + 1][lr] = qv.y;
    Qs[lk + 2][lr] = qv.z; Qs[lk + 3][lr] = qv.w;
    Ks[lk + 0][lr] = kv.x; Ks[lk + 1][lr] = kv.y;
    Ks[lk + 2][lr] = kv.z; Ks[lk + 3][lr] = kv.w;
    __syncthreads();
#pragma unroll
    for (int k = 0; k < 16; ++k) {
      const float4 a  = *(const float4*)&Qs[k][tm];
      const float4 bb = *(const float4*)&Ks[k][tn];
      const float aa[4] = {a.x, a.y, a.z, a.w};
      const float bv4[4] = {bb.x, bb.y, bb.z, bb.w};
#pragma unroll
      for (int r = 0; r < 4; ++r)
#pragma unroll
        for (int j = 0; j < 4; ++j)
          acc[r][j] = fmaf(aa[r], bv4[j], acc[r][j]);
    }
    __syncthreads();
  }
  float* ep = epart + ((size_t)b * 8 + ks) * 16384;
#pragma unroll
  for (int r = 0; r < 4; ++r) {
    float4 o;
    o.x = acc[r][0]; o.y = acc[r][1]; o.z = acc[r][2]; o.w = acc[r][3];
    *(float4*)&ep[(c0 + tm + r) * 128 + d0 + tn] = o;
  }
}

// ---------------- Kernel 3: reduce + softmax + M = A@Wv --------------------
// grid (8), 256 threads. E padded to stride 129 (kills 32-way row-scan conflict)
__global__ __launch_bounds__(256) void k_softmax_M(
    const float* __restrict__ epart, const float* __restrict__ Wv,
    const float* __restrict__ bv, float* __restrict__ Mbuf,
    float* __restrict__ outbb) {
  __shared__ float E[128][129];
  const int t = threadIdx.x;
  const int b = blockIdx.x;
  // deterministic K-split reduction
  for (int idx = t; idx < 16384; idx += 256) {
    float s = 0.f;
#pragma unroll
    for (int p = 0; p < 8; ++p)
      s += epart[((size_t)b * 8 + p) * 16384 + idx];
    E[idx >> 7][idx & 127] = s;
  }
  __syncthreads();
  // softmax(rowmax - e) == exp(rowmin - e) / sum(exp(rowmin - e))
  if (t < 128) {
    float mn = E[t][0];
    for (int d = 1; d < 128; ++d) mn = fminf(mn, E[t][d]);
    float s = 0.f;
    for (int d = 0; d < 128; ++d) s += expf(mn - E[t][d]);
    const float inv = 1.f / s;
    float ob = 0.f;
    for (int d = 0; d < 128; ++d) {
      const float a = expf(mn - E[t][d]) * inv;
      E[t][d] = a;
      ob = fmaf(a, bv[d], ob);
    }
    outbb[b * 128 + t] = ob;
  }
  __syncthreads();
  // M[c][i] = sum_d A[c][d] * Wv[d][i]
  for (int idx = t; idx < 16384; idx += 256) {
    const int c = idx >> 7, i = idx & 127;
    float s = 0.f;
    for (int d = 0; d < 128; ++d)
      s = fmaf(E[c][d], Wv[d * 128 + i], s);
    Mbuf[(size_t)b * 16384 + idx] = s;
  }
}

// ---------------- Kernel 4: out = M @ X + bias -----------------------------
// BM=128 BN=64 BK=16, K=128, fully coalesced. grid (256, 1, 8)
__global__ __launch_bounds__(256) void k_out(
    const float* __restrict__ x, const float* __restrict__ Mbuf,
    const float* __restrict__ outbb, float* __restrict__ out) {
  __shared__ float As[16][128];
  __shared__ float Bs[16][64];
  const int t  = threadIdx.x;
  const int nt = blockIdx.x;   // 0..255
  const int b  = blockIdx.z;
  const float* xb = x + (size_t)b * 2097152;
  const float* Mb = Mbuf + (size_t)b * 16384;
  float* ob = out + (size_t)b * 2097152;

  const int tm = (t >> 4) * 8;
  const int tn = (t & 15) * 4;
  const int am = t >> 1;
  const int ak = (t & 1) * 8;
  const int bkk = t >> 4;
  const int bn  = (t & 15) * 4;
  const int n_base = nt * 64;

  float acc[8][4];
#pragma unroll
  for (int r = 0; r < 8; ++r)
#pragma unroll
    for (int j = 0; j < 4; ++j) acc[r][j] = 0.f;

  for (int kk = 0; kk < 128; kk += 16) {
    const float4 a0 = *(const float4*)&Mb[am * 128 + kk + ak];
    const float4 a1 = *(const float4*)&Mb[am * 128 + kk + ak + 4];
    As[ak + 0][am] = a0.x; As[ak + 1][am] = a0.y;
    As[ak + 2][am] = a0.z; As[ak + 3][am] = a0.w;
    As[ak + 4][am] = a1.x; As[ak + 5][am] = a1.y;
    As[ak + 6][am] = a1.z; As[ak + 7][am] = a1.w;
    const float4 bv4 = *(const float4*)&xb[(kk + bkk) * 16384 + n_base + bn];
    *(float4*)&Bs[bkk][bn] = bv4;
    __syncthreads();
#pragma unroll
    for (int k = 0; k < 16; ++k) {
      const float4 av0 = *(const float4*)&As[k][tm];
      const float4 av1 = *(const float4*)&As[k][tm + 4];
      const float4 bq4 = *(const float4*)&Bs[k][tn];
      const float aa[8] = {av0.x, av0.y, av0.z, av0.w,
                           av1.x, av1.y, av1.z, av1.w};
      const float bb[4] = {bq4.x, bq4.y, bq4.z, bq4.w};
#pragma unroll
      for (int r = 0; r < 8; ++r)
#pragma unroll
        for (int j = 0; j < 4; ++j)
          acc[r][j] = fmaf(aa[r], bb[j], acc[r][j]);
    }
    __syncthreads();
  }
#pragma unroll
  for (int r = 0; r < 8; ++r) {
    const int row = tm + r;
    const float bias = outbb[b * 128 + row];
    float4 o;
    o.x = acc[r][0] + bias; o.y = acc[r][1] + bias;
    o.z = acc[r][2] + bias; o.w = acc[r][3] + bias;
    *(float4*)&ob[row * 16384 + n_base + tn] = o;
  }
}

// ---------------------------------------------------------------------------
extern "C" void kernel_launch(void* const* d_in, const int* in_sizes, int n_in,
                              void* d_out, int out_size, void* d_ws, size_t ws_size,
                              hipStream_t stream) {
  const float* x  = (const float*)d_in[0];
  const float* Wq = (const float*)d_in[1];
  const float* bq = (const float*)d_in[2];
  const float* Wk = (const float*)d_in[3];
  const float* bk = (const float*)d_in[4];
  const float* Wv = (const float*)d_in[5];
  const float* bv = (const float*)d_in[6];
  float* out = (float*)d_out;
  char* ws = (char*)d_ws;

  float* qbuf  = (float*)(ws);                  // 8*128*4096*4 = 16 MiB
  float* kbuf  = (float*)(ws + 16777216);       // 16 MiB
  float* epart = (float*)(ws + 33554432);       // 8*8*128*128*4 = 4 MiB
  float* Mbuf  = (float*)(ws + 37748736);       // 512 KiB
  float* outbb = (float*)(ws + 38273024);       // 4 KiB

  hipLaunchKernelGGL(k_qkconv, dim3(64, 2, 8), dim3(256), 0, stream,
                     x, Wq, Wk, bq, bk, qbuf, kbuf);
  hipLaunchKernelGGL(k_energy, dim3(4, 8, 8), dim3(256), 0, stream,
                     qbuf, kbuf, epart);
  hipLaunchKernelGGL(k_softmax_M, dim3(8), dim3(256), 0, stream,
                     epart, Wv, bv, Mbuf, outbb);
  hipLaunchKernelGGL(k_out, dim3(256, 1, 8), dim3(256), 0, stream,
                     x, Mbuf, outbb, out);
}

// Round 2
// 118.840 us; speedup vs baseline: 2.8240x; 2.8240x over previous
//
#include <hip/hip_runtime.h>
#include <math.h>

// ---------------------------------------------------------------------------
// CAM module, MFMA version.
//   q = conv2x2s2(x,Wq)+bq ; k = conv2x2s2(x,Wk)+bk        (bf16 hi/lo split)
//   energy = q @ k^T                                        (bf16 hi/lo split)
//   A = softmax(rowmin - energy) ; M = A@Wv ; ob = A@bv     (fp32)
//   out = M @ X + ob                                        (plain bf16 MFMA)
// ---------------------------------------------------------------------------

typedef float f32x4 __attribute__((ext_vector_type(4)));
typedef short s16x8 __attribute__((ext_vector_type(8)));

__device__ __forceinline__ unsigned short f2bf(float f) {
  union { float f; unsigned u; } v; v.f = f;
  unsigned r = v.u + 0x7FFFu + ((v.u >> 16) & 1u);
  return (unsigned short)(r >> 16);
}
__device__ __forceinline__ float bf2f(unsigned short h) {
  union { unsigned u; float f; } v; v.u = ((unsigned)h) << 16;
  return v.f;
}
__device__ __forceinline__ unsigned pack2(unsigned short a, unsigned short b) {
  return (unsigned)a | ((unsigned)b << 16);
}

union U16x16 { unsigned short us[16]; uint4 v4[2]; };

// stage 16 consecutive fp32 -> hi/lo bf16 into padded-40 LDS row
__device__ __forceinline__ void stage_row16(unsigned short* H, unsigned short* L,
                                            int idx, const float* src) {
  float w[16];
  *(float4*)&w[0]  = *(const float4*)&src[0];
  *(float4*)&w[4]  = *(const float4*)&src[4];
  *(float4*)&w[8]  = *(const float4*)&src[8];
  *(float4*)&w[12] = *(const float4*)&src[12];
  U16x16 hi, lo;
#pragma unroll
  for (int i = 0; i < 16; ++i) {
    hi.us[i] = f2bf(w[i]);
    lo.us[i] = f2bf(w[i] - bf2f(hi.us[i]));
  }
  *(uint4*)&H[idx]     = hi.v4[0];
  *(uint4*)&H[idx + 8] = hi.v4[1];
  *(uint4*)&L[idx]     = lo.v4[0];
  *(uint4*)&L[idx + 8] = lo.v4[1];
}

__device__ __forceinline__ void stage_row16_hi(unsigned short* H, int idx,
                                               const float* src) {
  float w[16];
  *(float4*)&w[0]  = *(const float4*)&src[0];
  *(float4*)&w[4]  = *(const float4*)&src[4];
  *(float4*)&w[8]  = *(const float4*)&src[8];
  *(float4*)&w[12] = *(const float4*)&src[12];
  U16x16 hi;
#pragma unroll
  for (int i = 0; i < 16; ++i) hi.us[i] = f2bf(w[i]);
  *(uint4*)&H[idx]     = hi.v4[0];
  *(uint4*)&H[idx + 8] = hi.v4[1];
}

// stage one float4 of x (cols c..c+3 = 2 output-cols x kw 0/1) into B tiles
__device__ __forceinline__ void stage_pair(unsigned short* Bh, unsigned short* Bl,
                                           int nl, int kloc, float4 v) {
  unsigned short hx = f2bf(v.x), hy = f2bf(v.y), hz = f2bf(v.z), hw = f2bf(v.w);
  unsigned short lx = f2bf(v.x - bf2f(hx)), ly = f2bf(v.y - bf2f(hy));
  unsigned short lz = f2bf(v.z - bf2f(hz)), lw = f2bf(v.w - bf2f(hw));
  *(unsigned*)&Bh[nl * 40 + kloc]        = pack2(hx, hy);
  *(unsigned*)&Bh[(nl + 1) * 40 + kloc]  = pack2(hz, hw);
  *(unsigned*)&Bl[nl * 40 + kloc]        = pack2(lx, ly);
  *(unsigned*)&Bl[(nl + 1) * 40 + kloc]  = pack2(lz, lw);
}

// ---------------- Kernel 1: stacked q/k conv via split-bf16 MFMA -----------
// C[256][128-tile] = [Wq;Wk](256x512) @ P(512x4096-tile), per batch.
// grid (32 n-tiles, 8 b), 512 threads = 8 waves (4x2 of 64x64).
__global__ __launch_bounds__(512) void k_qkconv(
    const float* __restrict__ x, const float* __restrict__ Wq,
    const float* __restrict__ Wk, const float* __restrict__ bq,
    const float* __restrict__ bk, float* __restrict__ qbuf,
    float* __restrict__ kbuf) {
  __shared__ unsigned short Ah[256 * 40], Al[256 * 40];
  __shared__ unsigned short Bh[128 * 40], Bl[128 * 40];
  const int t = threadIdx.x;
  const int nt = blockIdx.x;
  const int b  = blockIdx.y;
  const int wid = t >> 6, lane = t & 63;
  const int wr = wid >> 1, wc = wid & 1;
  const int lrow = lane & 15, lkb = lane >> 4;

  // staging assignments
  const int am = t >> 1, ak0 = (t & 1) * 16;           // A: W row, k-offset
  const int bci = t >> 6;                               // B: ci within K-tile
  const int bridx = (t >> 4) & 3;                       // B: x-row index 0..3
  const int bc0 = (t & 15) * 4;                         // B: col offset
  const int kh = bridx & 1, ohl = bridx >> 1;
  const int kloc_b = bci * 4 + kh * 2;

  const float* xb = x + ((size_t)b << 21);
  const float* Wrow = (am < 128) ? (Wq + (size_t)am * 512)
                                 : (Wk + (size_t)(am - 128) * 512);

  f32x4 acc[4][4];
#pragma unroll
  for (int m = 0; m < 4; ++m)
#pragma unroll
    for (int n = 0; n < 4; ++n) acc[m][n] = (f32x4){0.f, 0.f, 0.f, 0.f};

  for (int step = 0; step < 16; ++step) {
    const int kk = step * 32;
    // A staging: 16 floats of W row
    stage_row16(Ah, Al, am * 40 + ak0, &Wrow[kk + ak0]);
    // B staging: x rows -> patch tile (transposed, n-major)
    {
      const float* xr = xb + (size_t)(step * 8 + bci) * 16384 + (nt * 4 + bridx) * 128;
      float4 v1 = *(const float4*)&xr[bc0];
      float4 v2 = *(const float4*)&xr[64 + bc0];
      stage_pair(Bh, Bl, ohl * 64 + (bc0 >> 1), kloc_b, v1);
      stage_pair(Bh, Bl, ohl * 64 + 32 + (bc0 >> 1), kloc_b, v2);
    }
    __syncthreads();
    s16x8 afh[4], afl[4], bfh[4], bfl[4];
#pragma unroll
    for (int m = 0; m < 4; ++m) {
      const int aidx = (wr * 64 + m * 16 + lrow) * 40 + lkb * 8;
      afh[m] = *(const s16x8*)&Ah[aidx];
      afl[m] = *(const s16x8*)&Al[aidx];
    }
#pragma unroll
    for (int n = 0; n < 4; ++n) {
      const int bidx = (wc * 64 + n * 16 + lrow) * 40 + lkb * 8;
      bfh[n] = *(const s16x8*)&Bh[bidx];
      bfl[n] = *(const s16x8*)&Bl[bidx];
    }
#pragma unroll
    for (int m = 0; m < 4; ++m)
#pragma unroll
      for (int n = 0; n < 4; ++n) {
        acc[m][n] = __builtin_amdgcn_mfma_f32_16x16x32_bf16(afh[m], bfh[n], acc[m][n], 0, 0, 0);
        acc[m][n] = __builtin_amdgcn_mfma_f32_16x16x32_bf16(afh[m], bfl[n], acc[m][n], 0, 0, 0);
        acc[m][n] = __builtin_amdgcn_mfma_f32_16x16x32_bf16(afl[m], bfh[n], acc[m][n], 0, 0, 0);
      }
    __syncthreads();
  }
  // epilogue: wr 0,1 -> q ; wr 2,3 -> k
  float* dst = (wr < 2) ? qbuf : kbuf;
  const float* bias = (wr < 2) ? bq : bk;
  const int rbase = ((wr < 2) ? wr : (wr - 2)) * 64;
#pragma unroll
  for (int m = 0; m < 4; ++m) {
    const int r0 = rbase + m * 16 + (lane >> 4) * 4;
#pragma unroll
    for (int n = 0; n < 4; ++n) {
      const int gc = nt * 128 + wc * 64 + n * 16 + (lane & 15);
#pragma unroll
      for (int i = 0; i < 4; ++i) {
        const int row = r0 + i;
        dst[(size_t)b * 524288 + (size_t)row * 4096 + gc] = acc[m][n][i] + bias[row];
      }
    }
  }
}

// ---------------- Kernel 2: energy partials via split-bf16 MFMA ------------
// epart[b][ks][128][128] = q[:, ks*512:+512] @ k^T. grid (8 ks, 8 b), 256 thr.
__global__ __launch_bounds__(256) void k_energy(
    const float* __restrict__ qbuf, const float* __restrict__ kbuf,
    float* __restrict__ epart) {
  __shared__ unsigned short Qh[128 * 40], Ql[128 * 40];
  __shared__ unsigned short Kh[128 * 40], Kl[128 * 40];
  const int t = threadIdx.x;
  const int ks = blockIdx.x, b = blockIdx.y;
  const int wid = t >> 6, lane = t & 63;
  const int wr = wid >> 1, wc = wid & 1;
  const int lrow = lane & 15, lkb = lane >> 4;
  const int srow = t >> 1, skl0 = (t & 1) * 16;

  const float* qrow = qbuf + (size_t)b * 524288 + (size_t)srow * 4096 + ks * 512;
  const float* krow = kbuf + (size_t)b * 524288 + (size_t)srow * 4096 + ks * 512;

  f32x4 acc[4][4];
#pragma unroll
  for (int m = 0; m < 4; ++m)
#pragma unroll
    for (int n = 0; n < 4; ++n) acc[m][n] = (f32x4){0.f, 0.f, 0.f, 0.f};

  for (int step = 0; step < 16; ++step) {
    stage_row16(Qh, Ql, srow * 40 + skl0, &qrow[step * 32 + skl0]);
    stage_row16(Kh, Kl, srow * 40 + skl0, &krow[step * 32 + skl0]);
    __syncthreads();
    s16x8 afh[4], afl[4], bfh[4], bfl[4];
#pragma unroll
    for (int m = 0; m < 4; ++m) {
      const int aidx = (wr * 64 + m * 16 + lrow) * 40 + lkb * 8;
      afh[m] = *(const s16x8*)&Qh[aidx];
      afl[m] = *(const s16x8*)&Ql[aidx];
    }
#pragma unroll
    for (int n = 0; n < 4; ++n) {
      const int bidx = (wc * 64 + n * 16 + lrow) * 40 + lkb * 8;
      bfh[n] = *(const s16x8*)&Kh[bidx];
      bfl[n] = *(const s16x8*)&Kl[bidx];
    }
#pragma unroll
    for (int m = 0; m < 4; ++m)
#pragma unroll
      for (int n = 0; n < 4; ++n) {
        acc[m][n] = __builtin_amdgcn_mfma_f32_16x16x32_bf16(afh[m], bfh[n], acc[m][n], 0, 0, 0);
        acc[m][n] = __builtin_amdgcn_mfma_f32_16x16x32_bf16(afh[m], bfl[n], acc[m][n], 0, 0, 0);
        acc[m][n] = __builtin_amdgcn_mfma_f32_16x16x32_bf16(afl[m], bfh[n], acc[m][n], 0, 0, 0);
      }
    __syncthreads();
  }
  float* ep = epart + ((size_t)b * 8 + ks) * 16384;
#pragma unroll
  for (int m = 0; m < 4; ++m) {
    const int r0 = wr * 64 + m * 16 + (lane >> 4) * 4;
#pragma unroll
    for (int n = 0; n < 4; ++n) {
      const int col = wc * 64 + n * 16 + (lane & 15);
#pragma unroll
      for (int i = 0; i < 4; ++i) ep[(size_t)(r0 + i) * 128 + col] = acc[m][n][i];
    }
  }
}

// ---------------- Kernel 3: reduce + softmax + M = A@Wv, ob = A@bv ---------
// wave per row c. grid(256): b = blk>>5, c = (blk&31)*4 + wid. 256 thr.
__global__ __launch_bounds__(256) void k_softmax_M(
    const float* __restrict__ epart, const float* __restrict__ Wv,
    const float* __restrict__ bv, float* __restrict__ Mbuf,
    float* __restrict__ outbb) {
  __shared__ float As[4][128];
  const int t = threadIdx.x;
  const int wid = t >> 6, lane = t & 63;
  const int b = blockIdx.x >> 5;
  const int c = (blockIdx.x & 31) * 4 + wid;
  const int d0 = lane * 2;

  float2 s = make_float2(0.f, 0.f);
#pragma unroll
  for (int p = 0; p < 8; ++p) {
    float2 e = *(const float2*)&epart[((size_t)b * 8 + p) * 16384 + c * 128 + d0];
    s.x += e.x; s.y += e.y;
  }
  float mn = fminf(s.x, s.y);
#pragma unroll
  for (int off = 1; off < 64; off <<= 1) mn = fminf(mn, __shfl_xor(mn, off));
  const float p0 = expf(mn - s.x);
  const float p1 = expf(mn - s.y);
  float tot = p0 + p1;
#pragma unroll
  for (int off = 1; off < 64; off <<= 1) tot += __shfl_xor(tot, off);
  const float inv = 1.f / tot;
  const float a0 = p0 * inv, a1 = p1 * inv;

  const float2 bvv = *(const float2*)&bv[d0];
  float ob = a0 * bvv.x + a1 * bvv.y;
#pragma unroll
  for (int off = 1; off < 64; off <<= 1) ob += __shfl_xor(ob, off);
  if (lane == 0) outbb[b * 128 + c] = ob;

  As[wid][d0] = a0;
  As[wid][d0 + 1] = a1;   // wave-local write->read, lockstep-safe
  float m0 = 0.f, m1 = 0.f;
  for (int d = 0; d < 128; ++d) {
    const float a = As[wid][d];
    const float2 wv = *(const float2*)&Wv[d * 128 + d0];
    m0 = fmaf(a, wv.x, m0);
    m1 = fmaf(a, wv.y, m1);
  }
  *(float2*)&Mbuf[(size_t)b * 16384 + c * 128 + d0] = make_float2(m0, m1);
}

// ---------------- Kernel 4: out = M @ X + ob, plain bf16 MFMA --------------
// grid (128 n-tiles, 8 b), 256 thr = 4 waves (2x2 of 64x64). K=128.
__global__ __launch_bounds__(256) void k_out(
    const float* __restrict__ x, const float* __restrict__ Mbuf,
    const float* __restrict__ outbb, float* __restrict__ out) {
  __shared__ unsigned short Ms[128 * 40];
  __shared__ unsigned short Xs[128 * 40];
  const int t = threadIdx.x;
  const int nt = blockIdx.x, b = blockIdx.y;
  const int wid = t >> 6, lane = t & 63;
  const int wr = wid >> 1, wc = wid & 1;
  const int lrow = lane & 15, lkb = lane >> 4;
  const int am = t >> 1, ak0 = (t & 1) * 16;
  const int xkl = (t >> 5) * 4;           // +q -> k-row
  const int xc0 = (t & 31) * 4;           // col offset

  const float* xb = x + ((size_t)b << 21);
  const float* Mb = Mbuf + (size_t)b * 16384;
  float* ob = out + ((size_t)b << 21);

  f32x4 acc[4][4];
#pragma unroll
  for (int m = 0; m < 4; ++m)
#pragma unroll
    for (int n = 0; n < 4; ++n) acc[m][n] = (f32x4){0.f, 0.f, 0.f, 0.f};

  for (int step = 0; step < 4; ++step) {
    const int kk = step * 32;
    stage_row16_hi(Ms, am * 40 + ak0, &Mb[am * 128 + kk + ak0]);
#pragma unroll
    for (int q = 0; q < 4; ++q) {
      const int kl = xkl + q;
      float4 v = *(const float4*)&xb[(size_t)(kk + kl) * 16384 + nt * 128 + xc0];
      Xs[(xc0 + 0) * 40 + kl] = f2bf(v.x);
      Xs[(xc0 + 1) * 40 + kl] = f2bf(v.y);
      Xs[(xc0 + 2) * 40 + kl] = f2bf(v.z);
      Xs[(xc0 + 3) * 40 + kl] = f2bf(v.w);
    }
    __syncthreads();
    s16x8 af[4], bf[4];
#pragma unroll
    for (int m = 0; m < 4; ++m)
      af[m] = *(const s16x8*)&Ms[(wr * 64 + m * 16 + lrow) * 40 + lkb * 8];
#pragma unroll
    for (int n = 0; n < 4; ++n)
      bf[n] = *(const s16x8*)&Xs[(wc * 64 + n * 16 + lrow) * 40 + lkb * 8];
#pragma unroll
    for (int m = 0; m < 4; ++m)
#pragma unroll
      for (int n = 0; n < 4; ++n)
        acc[m][n] = __builtin_amdgcn_mfma_f32_16x16x32_bf16(af[m], bf[n], acc[m][n], 0, 0, 0);
    __syncthreads();
  }
#pragma unroll
  for (int m = 0; m < 4; ++m) {
    const int r0 = wr * 64 + m * 16 + (lane >> 4) * 4;
#pragma unroll
    for (int n = 0; n < 4; ++n) {
      const int gc = nt * 128 + wc * 64 + n * 16 + (lane & 15);
#pragma unroll
      for (int i = 0; i < 4; ++i) {
        const int row = r0 + i;
        ob[(size_t)row * 16384 + gc] = acc[m][n][i] + outbb[b * 128 + row];
      }
    }
  }
}

// ---------------------------------------------------------------------------
extern "C" void kernel_launch(void* const* d_in, const int* in_sizes, int n_in,
                              void* d_out, int out_size, void* d_ws, size_t ws_size,
                              hipStream_t stream) {
  const float* x  = (const float*)d_in[0];
  const float* Wq = (const float*)d_in[1];
  const float* bq = (const float*)d_in[2];
  const float* Wk = (const float*)d_in[3];
  const float* bk = (const float*)d_in[4];
  const float* Wv = (const float*)d_in[5];
  const float* bv = (const float*)d_in[6];
  float* out = (float*)d_out;
  char* ws = (char*)d_ws;

  float* qbuf  = (float*)(ws);                  // 16 MiB
  float* kbuf  = (float*)(ws + 16777216);       // 16 MiB
  float* epart = (float*)(ws + 33554432);       // 8*8*128*128*4 = 4 MiB
  float* Mbuf  = (float*)(ws + 37748736);       // 512 KiB
  float* outbb = (float*)(ws + 38273024);       // 4 KiB

  hipLaunchKernelGGL(k_qkconv, dim3(32, 8), dim3(512), 0, stream,
                     x, Wq, Wk, bq, bk, qbuf, kbuf);
  hipLaunchKernelGGL(k_energy, dim3(8, 8), dim3(256), 0, stream,
                     qbuf, kbuf, epart);
  hipLaunchKernelGGL(k_softmax_M, dim3(256), dim3(256), 0, stream,
                     epart, Wv, bv, Mbuf, outbb);
  hipLaunchKernelGGL(k_out, dim3(128, 8), dim3(256), 0, stream,
                     x, Mbuf, outbb, out);
}

// Round 3
// 93.955 us; speedup vs baseline: 3.5720x; 1.2649x over previous
//
#include <hip/hip_runtime.h>
#include <math.h>

// ---------------------------------------------------------------------------
// CAM module, fused MFMA version.
//   k_prep:        Wq,Wk -> tiled hi/lo bf16 (staging needs no conversion)
//   k_conv_energy: C=[Wq;Wk]@P per 64-col tile  ->  repack hi/lo in LDS ->
//                  epart[b][nt] = q_tile @ k_tile^T   (q/k never hit HBM)
//   k_softmax_M:   reduce 64 partials, softmax(rowmin-e), M=A@Wv, ob=A@bv
//   k_out:         out = M @ X + ob   (plain bf16 MFMA, HBM-bound)
// ---------------------------------------------------------------------------

typedef float f32x4 __attribute__((ext_vector_type(4)));
typedef short s16x8 __attribute__((ext_vector_type(8)));

__device__ __forceinline__ unsigned short f2bf(float f) {
  union { float f; unsigned u; } v; v.f = f;
  unsigned r = v.u + 0x7FFFu + ((v.u >> 16) & 1u);
  return (unsigned short)(r >> 16);
}
__device__ __forceinline__ float bf2f(unsigned short h) {
  union { unsigned u; float f; } v; v.u = ((unsigned)h) << 16;
  return v.f;
}
__device__ __forceinline__ unsigned pack2(unsigned short a, unsigned short b) {
  return (unsigned)a | ((unsigned)b << 16);
}

// stage one float4 of x (cols c..c+3 = 2 output-cols x kw 0/1) into B tiles
__device__ __forceinline__ void stage_pair(unsigned short* Bh, unsigned short* Bl,
                                           int nl, int kloc, float4 v) {
  unsigned short hx = f2bf(v.x), hy = f2bf(v.y), hz = f2bf(v.z), hw = f2bf(v.w);
  unsigned short lx = f2bf(v.x - bf2f(hx)), ly = f2bf(v.y - bf2f(hy));
  unsigned short lz = f2bf(v.z - bf2f(hz)), lw = f2bf(v.w - bf2f(hw));
  *(unsigned*)&Bh[nl * 40 + kloc]       = pack2(hx, hy);
  *(unsigned*)&Bh[(nl + 1) * 40 + kloc] = pack2(hz, hw);
  *(unsigned*)&Bl[nl * 40 + kloc]       = pack2(lx, ly);
  *(unsigned*)&Bl[(nl + 1) * 40 + kloc] = pack2(lz, lw);
}

// ---------------- Kernel 0: W -> tiled hi/lo bf16 --------------------------
// Wt[step][row][koff], step = k/32. 16*256*32 u16 per plane. grid 128x256.
__global__ __launch_bounds__(256) void k_prep(
    const float* __restrict__ Wq, const float* __restrict__ Wk,
    unsigned short* __restrict__ Wth, unsigned short* __restrict__ Wtl) {
  const int f = (blockIdx.x * 256 + threadIdx.x) * 4;
  const int row = f >> 9;
  const int k   = f & 511;
  const float* src = (row < 128) ? &Wq[row * 512 + k] : &Wk[(row - 128) * 512 + k];
  float4 v = *(const float4*)src;
  unsigned short h0 = f2bf(v.x), h1 = f2bf(v.y), h2 = f2bf(v.z), h3 = f2bf(v.w);
  unsigned short l0 = f2bf(v.x - bf2f(h0)), l1 = f2bf(v.y - bf2f(h1));
  unsigned short l2 = f2bf(v.z - bf2f(h2)), l3 = f2bf(v.w - bf2f(h3));
  const int di = (k >> 5) * 8192 + row * 32 + (k & 31);
  *(ushort4*)&Wth[di] = make_ushort4(h0, h1, h2, h3);
  *(ushort4*)&Wtl[di] = make_ushort4(l0, l1, l2, l3);
}

// ---------------- Kernel 1: fused conv + energy partial --------------------
// grid (64 nt, 8 b), 256 thr = 4 waves. Tile: rows 0-255 (q:0-127,k:128-255),
// cols nt*64..+63, K=512 in 16 steps of 32 (split-bf16, 3 MFMA/frag).
// Then: repack C+bias -> hi/lo LDS (XOR swizzle), energy partial K=64.
__global__ __launch_bounds__(256, 2) void k_conv_energy(
    const float* __restrict__ x,
    const unsigned short* __restrict__ Wth, const unsigned short* __restrict__ Wtl,
    const float* __restrict__ bq, const float* __restrict__ bk,
    float* __restrict__ epart) {
  __shared__ unsigned short LDS[32768];   // 64 KiB, unioned across phases
  unsigned short* Ah = LDS;               // 256*40
  unsigned short* Al = LDS + 10240;       // 256*40
  unsigned short* Bh = LDS + 20480;       // 64*40
  unsigned short* Bl = LDS + 23040;       // 64*40
  unsigned short* Th = LDS;               // 256*64 (phase 2+)
  unsigned short* Tl = LDS + 16384;       // 256*64

  const int t = threadIdx.x;
  const int nt = blockIdx.x, b = blockIdx.y;
  const int w = t >> 6, lane = t & 63;
  const int lrow = lane & 15, lkb = lane >> 4;

  // B-staging mapping: pair = (ci_local, kh); 16 threads cover 128 w-cols
  const int pp = t >> 4;
  const int ci_l = pp >> 1, kh = pp & 1;
  const int c0 = (t & 15) * 8;
  const int klb = ci_l * 4 + kh * 2;
  const float* xb = x + ((size_t)b << 21);

  f32x4 acc[4][4];
#pragma unroll
  for (int m = 0; m < 4; ++m)
#pragma unroll
    for (int n = 0; n < 4; ++n) acc[m][n] = (f32x4){0.f, 0.f, 0.f, 0.f};

  for (int step = 0; step < 16; ++step) {
    // A: pure uint4 copies of pre-tiled W hi/lo
    const uint4* gh = (const uint4*)(Wth + step * 8192);
    const uint4* gl = (const uint4*)(Wtl + step * 8192);
#pragma unroll
    for (int j = 0; j < 4; ++j) {
      const int c = t + 256 * j;
      const int row = c >> 2, ko = (c & 3) * 8;
      *(uint4*)&Ah[row * 40 + ko] = gh[c];
      *(uint4*)&Al[row * 40 + ko] = gl[c];
    }
    // B: x -> patch tile hi/lo (conversion in-kernel; x read once total)
    {
      const float* xr = xb + (size_t)(step * 8 + ci_l) * 16384 + (2 * nt + kh) * 128 + c0;
      float4 v1 = *(const float4*)&xr[0];
      float4 v2 = *(const float4*)&xr[4];
      stage_pair(Bh, Bl, c0 >> 1, klb, v1);
      stage_pair(Bh, Bl, (c0 >> 1) + 2, klb, v2);
    }
    __syncthreads();
    s16x8 afh[4], afl[4], bfh[4], bfl[4];
#pragma unroll
    for (int m = 0; m < 4; ++m) {
      const int aidx = (w * 64 + m * 16 + lrow) * 40 + lkb * 8;
      afh[m] = *(const s16x8*)&Ah[aidx];
      afl[m] = *(const s16x8*)&Al[aidx];
    }
#pragma unroll
    for (int n = 0; n < 4; ++n) {
      const int bidx = (n * 16 + lrow) * 40 + lkb * 8;
      bfh[n] = *(const s16x8*)&Bh[bidx];
      bfl[n] = *(const s16x8*)&Bl[bidx];
    }
#pragma unroll
    for (int m = 0; m < 4; ++m)
#pragma unroll
      for (int n = 0; n < 4; ++n) {
        acc[m][n] = __builtin_amdgcn_mfma_f32_16x16x32_bf16(afh[m], bfh[n], acc[m][n], 0, 0, 0);
        acc[m][n] = __builtin_amdgcn_mfma_f32_16x16x32_bf16(afh[m], bfl[n], acc[m][n], 0, 0, 0);
        acc[m][n] = __builtin_amdgcn_mfma_f32_16x16x32_bf16(afl[m], bfh[n], acc[m][n], 0, 0, 0);
      }
    __syncthreads();
  }

  // ---- phase 2: repack C+bias -> hi/lo bf16 LDS tile, XOR-swizzled -------
#pragma unroll
  for (int m = 0; m < 4; ++m) {
    const int r0 = w * 64 + m * 16 + (lane >> 4) * 4;
#pragma unroll
    for (int n = 0; n < 4; ++n) {
      const int c = n * 16 + lrow;
      const int c8 = c >> 3, c7 = c & 7;
#pragma unroll
      for (int i = 0; i < 4; ++i) {
        const int r = r0 + i;
        const float bias = (r < 128) ? bq[r] : bk[r - 128];
        const float vv = acc[m][n][i] + bias;
        const unsigned short h = f2bf(vv);
        const unsigned short l = f2bf(vv - bf2f(h));
        const int ad = r * 64 + (((c8 ^ (r & 7))) << 3) + c7;
        Th[ad] = h;
        Tl[ad] = l;
      }
    }
  }
  __syncthreads();

  // ---- phase 3: energy partial = q_tile(128x64) @ k_tile(128x64)^T --------
  f32x4 e[4][4];
#pragma unroll
  for (int m = 0; m < 4; ++m)
#pragma unroll
    for (int n = 0; n < 4; ++n) e[m][n] = (f32x4){0.f, 0.f, 0.f, 0.f};

  const int mrow0 = (w >> 1) * 64;       // q-half rows (0 or 64)
  const int nrow0 = 128 + (w & 1) * 64;  // k-half rows
#pragma unroll
  for (int ks = 0; ks < 2; ++ks) {
    const int c8 = ks * 4 + lkb;
    s16x8 qh[4], ql[4], kh8[4], kl8[4];
#pragma unroll
    for (int m = 0; m < 4; ++m) {
      const int r = mrow0 + m * 16 + lrow;
      const int ad = r * 64 + ((c8 ^ (r & 7)) << 3);
      qh[m] = *(const s16x8*)&Th[ad];
      ql[m] = *(const s16x8*)&Tl[ad];
    }
#pragma unroll
    for (int n = 0; n < 4; ++n) {
      const int r = nrow0 + n * 16 + lrow;
      const int ad = r * 64 + ((c8 ^ (r & 7)) << 3);
      kh8[n] = *(const s16x8*)&Th[ad];
      kl8[n] = *(const s16x8*)&Tl[ad];
    }
#pragma unroll
    for (int m = 0; m < 4; ++m)
#pragma unroll
      for (int n = 0; n < 4; ++n) {
        e[m][n] = __builtin_amdgcn_mfma_f32_16x16x32_bf16(qh[m], kh8[n], e[m][n], 0, 0, 0);
        e[m][n] = __builtin_amdgcn_mfma_f32_16x16x32_bf16(qh[m], kl8[n], e[m][n], 0, 0, 0);
        e[m][n] = __builtin_amdgcn_mfma_f32_16x16x32_bf16(ql[m], kh8[n], e[m][n], 0, 0, 0);
      }
  }
  float* ep = epart + ((size_t)b * 64 + nt) * 16384;
#pragma unroll
  for (int m = 0; m < 4; ++m) {
    const int qr = (w >> 1) * 64 + m * 16 + (lane >> 4) * 4;
#pragma unroll
    for (int n = 0; n < 4; ++n) {
      const int kr = (w & 1) * 64 + n * 16 + lrow;
#pragma unroll
      for (int i = 0; i < 4; ++i) ep[(size_t)(qr + i) * 128 + kr] = e[m][n][i];
    }
  }
}

// ---------------- Kernel 2: reduce + softmax + M = A@Wv, ob = A@bv ---------
// wave per row c. grid(256): b = blk>>5, c = (blk&31)*4 + wid. 256 thr.
__global__ __launch_bounds__(256) void k_softmax_M(
    const float* __restrict__ epart, const float* __restrict__ Wv,
    const float* __restrict__ bv, float* __restrict__ Mbuf,
    float* __restrict__ outbb) {
  __shared__ float As[4][128];
  const int t = threadIdx.x;
  const int wid = t >> 6, lane = t & 63;
  const int b = blockIdx.x >> 5;
  const int c = (blockIdx.x & 31) * 4 + wid;
  const int d0 = lane * 2;

  float2 s = make_float2(0.f, 0.f);
#pragma unroll 4
  for (int p = 0; p < 64; ++p) {
    float2 e = *(const float2*)&epart[((size_t)b * 64 + p) * 16384 + c * 128 + d0];
    s.x += e.x; s.y += e.y;
  }
  float mn = fminf(s.x, s.y);
#pragma unroll
  for (int off = 1; off < 64; off <<= 1) mn = fminf(mn, __shfl_xor(mn, off));
  const float p0 = expf(mn - s.x);
  const float p1 = expf(mn - s.y);
  float tot = p0 + p1;
#pragma unroll
  for (int off = 1; off < 64; off <<= 1) tot += __shfl_xor(tot, off);
  const float inv = 1.f / tot;
  const float a0 = p0 * inv, a1 = p1 * inv;

  const float2 bvv = *(const float2*)&bv[d0];
  float ob = a0 * bvv.x + a1 * bvv.y;
#pragma unroll
  for (int off = 1; off < 64; off <<= 1) ob += __shfl_xor(ob, off);
  if (lane == 0) outbb[b * 128 + c] = ob;

  As[wid][d0] = a0;
  As[wid][d0 + 1] = a1;   // wave-local write->read, lockstep-safe
  float m0 = 0.f, m1 = 0.f;
#pragma unroll 4
  for (int d = 0; d < 128; ++d) {
    const float a = As[wid][d];
    const float2 wv = *(const float2*)&Wv[d * 128 + d0];
    m0 = fmaf(a, wv.x, m0);
    m1 = fmaf(a, wv.y, m1);
  }
  *(float2*)&Mbuf[(size_t)b * 16384 + c * 128 + d0] = make_float2(m0, m1);
}

// ---------------- Kernel 3: out = M @ X + ob, plain bf16 MFMA --------------
// grid (128 n-tiles, 8 b), 256 thr = 4 waves (2x2 of 64x64). K=128.
__global__ __launch_bounds__(256) void k_out(
    const float* __restrict__ x, const float* __restrict__ Mbuf,
    const float* __restrict__ outbb, float* __restrict__ out) {
  __shared__ unsigned short Ms[128 * 40];
  __shared__ unsigned short Xs[128 * 40];
  const int t = threadIdx.x;
  const int nt = blockIdx.x, b = blockIdx.y;
  const int wid = t >> 6, lane = t & 63;
  const int wr = wid >> 1, wc = wid & 1;
  const int lrow = lane & 15, lkb = lane >> 4;
  const int am = t >> 1, ak0 = (t & 1) * 16;
  const int xkl = (t >> 5) * 4;
  const int xc0 = (t & 31) * 4;

  const float* xb = x + ((size_t)b << 21);
  const float* Mb = Mbuf + (size_t)b * 16384;
  float* ob = out + ((size_t)b << 21);

  f32x4 acc[4][4];
#pragma unroll
  for (int m = 0; m < 4; ++m)
#pragma unroll
    for (int n = 0; n < 4; ++n) acc[m][n] = (f32x4){0.f, 0.f, 0.f, 0.f};

  for (int step = 0; step < 4; ++step) {
    const int kk = step * 32;
    {
      float w[16];
      *(float4*)&w[0]  = *(const float4*)&Mb[am * 128 + kk + ak0];
      *(float4*)&w[4]  = *(const float4*)&Mb[am * 128 + kk + ak0 + 4];
      *(float4*)&w[8]  = *(const float4*)&Mb[am * 128 + kk + ak0 + 8];
      *(float4*)&w[12] = *(const float4*)&Mb[am * 128 + kk + ak0 + 12];
      unsigned short hs[16];
#pragma unroll
      for (int i = 0; i < 16; ++i) hs[i] = f2bf(w[i]);
      *(uint4*)&Ms[am * 40 + ak0]     = *(uint4*)&hs[0];
      *(uint4*)&Ms[am * 40 + ak0 + 8] = *(uint4*)&hs[8];
    }
#pragma unroll
    for (int q = 0; q < 4; ++q) {
      const int kl = xkl + q;
      float4 v = *(const float4*)&xb[(size_t)(kk + kl) * 16384 + nt * 128 + xc0];
      Xs[(xc0 + 0) * 40 + kl] = f2bf(v.x);
      Xs[(xc0 + 1) * 40 + kl] = f2bf(v.y);
      Xs[(xc0 + 2) * 40 + kl] = f2bf(v.z);
      Xs[(xc0 + 3) * 40 + kl] = f2bf(v.w);
    }
    __syncthreads();
    s16x8 af[4], bf[4];
#pragma unroll
    for (int m = 0; m < 4; ++m)
      af[m] = *(const s16x8*)&Ms[(wr * 64 + m * 16 + lrow) * 40 + lkb * 8];
#pragma unroll
    for (int n = 0; n < 4; ++n)
      bf[n] = *(const s16x8*)&Xs[(wc * 64 + n * 16 + lrow) * 40 + lkb * 8];
#pragma unroll
    for (int m = 0; m < 4; ++m)
#pragma unroll
      for (int n = 0; n < 4; ++n)
        acc[m][n] = __builtin_amdgcn_mfma_f32_16x16x32_bf16(af[m], bf[n], acc[m][n], 0, 0, 0);
    __syncthreads();
  }
#pragma unroll
  for (int m = 0; m < 4; ++m) {
    const int r0 = wr * 64 + m * 16 + (lane >> 4) * 4;
#pragma unroll
    for (int n = 0; n < 4; ++n) {
      const int gc = nt * 128 + wc * 64 + n * 16 + (lane & 15);
#pragma unroll
      for (int i = 0; i < 4; ++i) {
        const int row = r0 + i;
        ob[(size_t)row * 16384 + gc] = acc[m][n][i] + outbb[b * 128 + row];
      }
    }
  }
}

// ---------------------------------------------------------------------------
extern "C" void kernel_launch(void* const* d_in, const int* in_sizes, int n_in,
                              void* d_out, int out_size, void* d_ws, size_t ws_size,
                              hipStream_t stream) {
  const float* x  = (const float*)d_in[0];
  const float* Wq = (const float*)d_in[1];
  const float* bq = (const float*)d_in[2];
  const float* Wk = (const float*)d_in[3];
  const float* bk = (const float*)d_in[4];
  const float* Wv = (const float*)d_in[5];
  const float* bv = (const float*)d_in[6];
  float* out = (float*)d_out;
  char* ws = (char*)d_ws;

  float* epart = (float*)ws;                         // 64*16384*4*8 = 32 MiB
  float* Mbuf  = (float*)(ws + 33554432);            // 512 KiB
  float* outbb = (float*)(ws + 34078720);            // 4 KiB
  unsigned short* Wth = (unsigned short*)(ws + 34082816);  // 256 KiB
  unsigned short* Wtl = (unsigned short*)(ws + 34344960);  // 256 KiB

  hipLaunchKernelGGL(k_prep, dim3(128), dim3(256), 0, stream, Wq, Wk, Wth, Wtl);
  hipLaunchKernelGGL(k_conv_energy, dim3(64, 8), dim3(256), 0, stream,
                     x, Wth, Wtl, bq, bk, epart);
  hipLaunchKernelGGL(k_softmax_M, dim3(256), dim3(256), 0, stream,
                     epart, Wv, bv, Mbuf, outbb);
  hipLaunchKernelGGL(k_out, dim3(128, 8), dim3(256), 0, stream,
                     x, Mbuf, outbb, out);
}